// Round 1
// baseline (253.672 us; speedup 1.0000x reference)
//
#include <hip/hip_runtime.h>

#define B_ 32
#define T_ 1024
#define D_ 1024
#define M_ (B_ * T_)
#define NT_ 8
#define BM_ 128
#define BN_ 128
#define BK_ 64
#define LSTR 72  // LDS row stride in bf16 elems (144 B: 16B-aligned, uniform-bank b128 reads)

typedef __attribute__((ext_vector_type(8))) short short8;
typedef __attribute__((ext_vector_type(4))) float f32x4;

__device__ __forceinline__ unsigned f2bf(float f) {
    union { float f; unsigned u; } v; v.f = f;
    return (v.u + 0x7FFFu + ((v.u >> 16) & 1u)) >> 16;  // RNE
}
__device__ __forceinline__ unsigned pack2(float a, float b) {
    return f2bf(a) | (f2bf(b) << 16);
}
__device__ __forceinline__ float fast_tanh(float x) {
    x = fminf(15.0f, fmaxf(-15.0f, x));
    float e = __expf(2.0f * x);
    return (e - 1.0f) * __fdividef(1.0f, e + 1.0f);
}

// ---------- kernel 1: dec = s_t @ W_s + b_s  (B x D) ----------
__global__ __launch_bounds__(256) void dec_kernel(
    const float* __restrict__ s_t, const float* __restrict__ W_s,
    const float* __restrict__ b_s, float* __restrict__ dec)
{
    __shared__ float s_lds[D_];
    const int b = blockIdx.x >> 2;
    const int d = (blockIdx.x & 3) * 256 + threadIdx.x;
    for (int i = threadIdx.x; i < D_; i += 256) s_lds[i] = s_t[b * D_ + i];
    __syncthreads();
    float acc = b_s[d];
#pragma unroll 8
    for (int k = 0; k < D_; ++k) acc += s_lds[k] * W_s[(size_t)k * D_ + d];
    dec[b * D_ + d] = acc;
}

// ---------- kernel 2: fused e_t GEMM ----------
// e_part[nt][m] = sum over n-tile nt of tanh(h@W_h + dec + cov*W_c) * V_w
__global__ __launch_bounds__(256, 2) void attn_gemm_kernel(
    const float* __restrict__ h_i, const float* __restrict__ W_h,
    const float* __restrict__ dec, const float* __restrict__ coverage,
    const float* __restrict__ W_c, const float* __restrict__ V_w,
    float* __restrict__ e_part)
{
    __shared__ __align__(16) unsigned short lA[BM_][LSTR];   // [row][k] bf16
    __shared__ __align__(16) unsigned short lB[BN_][LSTR];   // [n][k] bf16 (W_h transposed)

    const int tid = threadIdx.x;
    const int nt = blockIdx.x >> 8;    // mt-inner: XCD keeps one W_h panel L2-resident
    const int mt = blockIdx.x & 255;
    const int m0 = mt * BM_;
    const int n0 = nt * BN_;
    const int bb = m0 >> 10;           // batch index (BM divides T)

    const int wave = tid >> 6;
    const int lane = tid & 63;
    const int wr = wave >> 1, wc = wave & 1;  // 2x2 wave grid over 128x128
    const int lr = lane & 15;
    const int lk = lane >> 4;

    f32x4 acc[4][4];
    const f32x4 fzero = {0.f, 0.f, 0.f, 0.f};
#pragma unroll
    for (int i = 0; i < 4; ++i)
#pragma unroll
        for (int j = 0; j < 4; ++j) acc[i][j] = fzero;

    const int a_row = tid >> 4;
    const int a_k = (tid & 15) << 2;
    const float* hA = h_i + (size_t)m0 * D_;

    for (int k0 = 0; k0 < D_; k0 += BK_) {
        // stage A tile (128x64), fp32 -> bf16
#pragma unroll
        for (int p = 0; p < 8; ++p) {
            const int row = a_row + p * 16;
            const float4 v = *(const float4*)(hA + (size_t)row * D_ + (k0 + a_k));
            *(uint2*)&lA[row][a_k] = make_uint2(pack2(v.x, v.y), pack2(v.z, v.w));
        }
        // stage B tile (64x128) transposed into lB[n][k]
#pragma unroll
        for (int p = 0; p < 8; ++p) {
            const int task = tid + p * 256;
            const int n = task & 127;
            const int kg = task >> 7;  // 0..15
            const float* wp = W_h + (size_t)(k0 + kg * 4) * D_ + n0 + n;
            const float x0 = wp[0 * D_], x1 = wp[1 * D_], x2 = wp[2 * D_], x3 = wp[3 * D_];
            *(uint2*)&lB[n][kg * 4] = make_uint2(pack2(x0, x1), pack2(x2, x3));
        }
        __syncthreads();

        short8 af[2][4], bfr[2][4];
#pragma unroll
        for (int kk = 0; kk < 2; ++kk)
#pragma unroll
            for (int i = 0; i < 4; ++i) {
                af[kk][i]  = *(const short8*)&lA[wr * 64 + i * 16 + lr][kk * 32 + lk * 8];
                bfr[kk][i] = *(const short8*)&lB[wc * 64 + i * 16 + lr][kk * 32 + lk * 8];
            }
#pragma unroll
        for (int kk = 0; kk < 2; ++kk)
#pragma unroll
            for (int mi = 0; mi < 4; ++mi)
#pragma unroll
                for (int ni = 0; ni < 4; ++ni)
                    acc[mi][ni] = __builtin_amdgcn_mfma_f32_16x16x32_bf16(
                        af[kk][mi], bfr[kk][ni], acc[mi][ni], 0, 0, 0);
        __syncthreads();
    }

    // epilogue: features = acc + dec[n] + cov[m]*W_c[n]; e += tanh(f)*V_w[n]
    float esum[4][4];
    float covv[4][4];
#pragma unroll
    for (int mi = 0; mi < 4; ++mi)
#pragma unroll
        for (int r = 0; r < 4; ++r) {
            esum[mi][r] = 0.f;
            covv[mi][r] = coverage[m0 + wr * 64 + mi * 16 + lk * 4 + r];
        }
    const float* decb = dec + bb * D_;
#pragma unroll
    for (int ni = 0; ni < 4; ++ni) {
        const int n = n0 + wc * 64 + ni * 16 + lr;   // C/D col = lane&15
        const float vw = V_w[n];
        const float dc = decb[n];
        const float wcv = W_c[n];
#pragma unroll
        for (int mi = 0; mi < 4; ++mi)
#pragma unroll
            for (int r = 0; r < 4; ++r) {
                const float f = acc[mi][ni][r] + dc + covv[mi][r] * wcv;
                esum[mi][r] += fast_tanh(f) * vw;
            }
    }
    // reduce over the 16 col-lanes (lane&15)
#pragma unroll
    for (int off = 1; off <= 8; off <<= 1)
#pragma unroll
        for (int mi = 0; mi < 4; ++mi)
#pragma unroll
            for (int r = 0; r < 4; ++r)
                esum[mi][r] += __shfl_xor(esum[mi][r], off, 64);

    // combine wc=0/1 halves via LDS (reuse lA)
    float* e_lds = (float*)&lA[0][0];
    if (lr == 0) {
#pragma unroll
        for (int mi = 0; mi < 4; ++mi)
#pragma unroll
            for (int r = 0; r < 4; ++r)
                e_lds[wc * 128 + wr * 64 + mi * 16 + lk * 4 + r] = esum[mi][r];
    }
    __syncthreads();
    if (tid < 128)
        e_part[(size_t)nt * M_ + m0 + tid] = e_lds[tid] + e_lds[128 + tid];
}

// ---------- kernel 3: softmax over T per batch + coverage_new ----------
__global__ __launch_bounds__(256) void softmax_kernel(
    const float* __restrict__ e_part, const float* __restrict__ coverage,
    float* __restrict__ a_out, float* __restrict__ cov_out)
{
    const int b = blockIdx.x;
    const int tid = threadIdx.x;
    __shared__ float redmx[4], redsum[4];
    float e[4];
#pragma unroll
    for (int j = 0; j < 4; ++j) {
        const int t = tid + j * 256;
        float s = 0.f;
#pragma unroll
        for (int p = 0; p < NT_; ++p) s += e_part[(size_t)p * M_ + b * T_ + t];
        e[j] = s;
    }
    float mx = fmaxf(fmaxf(e[0], e[1]), fmaxf(e[2], e[3]));
#pragma unroll
    for (int off = 32; off > 0; off >>= 1) mx = fmaxf(mx, __shfl_xor(mx, off, 64));
    if ((tid & 63) == 0) redmx[tid >> 6] = mx;
    __syncthreads();
    mx = fmaxf(fmaxf(redmx[0], redmx[1]), fmaxf(redmx[2], redmx[3]));
    float p4[4];
    float ps = 0.f;
#pragma unroll
    for (int j = 0; j < 4; ++j) { p4[j] = __expf(e[j] - mx); ps += p4[j]; }
#pragma unroll
    for (int off = 32; off > 0; off >>= 1) ps += __shfl_xor(ps, off, 64);
    if ((tid & 63) == 0) redsum[tid >> 6] = ps;
    __syncthreads();
    ps = redsum[0] + redsum[1] + redsum[2] + redsum[3];
    const float inv = __fdividef(1.f, ps);
#pragma unroll
    for (int j = 0; j < 4; ++j) {
        const int idx = b * T_ + tid + j * 256;
        const float a = p4[j] * inv;
        a_out[idx] = a;
        cov_out[idx] = coverage[idx] + a;
    }
}

// ---------- kernel 4: context partials over T-chunks ----------
__global__ __launch_bounds__(256) void ctx_part_kernel(
    const float* __restrict__ h_i, const float* __restrict__ a_t,
    float* __restrict__ ctx_part)
{
    const int bid = blockIdx.x;     // B * 4(dchunk) * 4(tchunk)
    const int b = bid >> 4;
    const int dc = (bid >> 2) & 3;
    const int tc = bid & 3;
    const int tid = threadIdx.x;
    const int d = dc * 256 + tid;
    __shared__ float a_lds[256];
    a_lds[tid] = a_t[b * T_ + tc * 256 + tid];
    __syncthreads();
    const float* hp = h_i + ((size_t)(b * T_ + tc * 256)) * D_ + d;
    float acc = 0.f;
#pragma unroll 8
    for (int t = 0; t < 256; ++t) acc += a_lds[t] * hp[(size_t)t * D_];
    ctx_part[tc * (B_ * D_) + b * D_ + d] = acc;
}

// ---------- kernel 5: reduce context partials ----------
__global__ __launch_bounds__(256) void ctx_reduce_kernel(
    const float* __restrict__ ctx_part, float* __restrict__ out)
{
    const int i = blockIdx.x * 256 + threadIdx.x;
    out[i] = ctx_part[i] + ctx_part[B_ * D_ + i] + ctx_part[2 * B_ * D_ + i] +
             ctx_part[3 * B_ * D_ + i];
}

extern "C" void kernel_launch(void* const* d_in, const int* in_sizes, int n_in,
                              void* d_out, int out_size, void* d_ws, size_t ws_size,
                              hipStream_t stream)
{
    (void)in_sizes; (void)n_in; (void)out_size; (void)ws_size;
    const float* h_i      = (const float*)d_in[0];
    const float* s_t      = (const float*)d_in[1];
    const float* coverage = (const float*)d_in[2];
    const float* W_h      = (const float*)d_in[3];
    const float* W_s      = (const float*)d_in[4];
    const float* b_s      = (const float*)d_in[5];
    const float* W_c      = (const float*)d_in[6];
    const float* V_w      = (const float*)d_in[7];

    float* out     = (float*)d_out;
    float* ctx_out = out;                 // (B, D)
    float* a_out   = out + B_ * T_;       // (B, T)
    float* cov_out = out + 2 * B_ * T_;   // (B, T)

    float* ws       = (float*)d_ws;
    float* dec      = ws;                       // B*D
    float* e_part   = ws + B_ * D_;             // NT_*M_
    float* ctx_part = e_part + NT_ * M_;        // 4*B*D

    dec_kernel<<<B_ * 4, 256, 0, stream>>>(s_t, W_s, b_s, dec);
    attn_gemm_kernel<<<NT_ * (M_ / BM_), 256, 0, stream>>>(h_i, W_h, dec, coverage,
                                                           W_c, V_w, e_part);
    softmax_kernel<<<B_, 256, 0, stream>>>(e_part, coverage, a_out, cov_out);
    ctx_part_kernel<<<B_ * 16, 256, 0, stream>>>(h_i, a_out, ctx_part);
    ctx_reduce_kernel<<<(B_ * D_) / 256, 256, 0, stream>>>(ctx_part, ctx_out);
}

// Round 2
// 191.161 us; speedup vs baseline: 1.3270x; 1.3270x over previous
//
#include <hip/hip_runtime.h>

#define B_ 32
#define T_ 1024
#define D_ 1024
#define M_ (B_ * T_)
#define NT_ 8
#define BM_ 128
#define BN_ 128
#define BK_ 64
#define LSTR 72  // fallback-path LDS row stride (bf16 elems)

typedef __attribute__((ext_vector_type(8))) short short8;
typedef __attribute__((ext_vector_type(4))) float f32x4;

__device__ __forceinline__ unsigned f2bf(float f) {
    union { float f; unsigned u; } v; v.f = f;
    return (v.u + 0x7FFFu + ((v.u >> 16) & 1u)) >> 16;  // RNE
}
__device__ __forceinline__ unsigned pack2(float a, float b) {
    return f2bf(a) | (f2bf(b) << 16);
}
__device__ __forceinline__ float fast_tanh(float x) {
    x = fminf(15.0f, fmaxf(-15.0f, x));
    float e = __expf(2.0f * x);
    return (e - 1.0f) * __fdividef(1.0f, e + 1.0f);
}

// ---------- prep A: h_i fp32 -> bf16 (row-major, 8 elems/thread/iter) ----------
__global__ __launch_bounds__(256) void conv_h_kernel(
    const float* __restrict__ in, uint4* __restrict__ out)
{
    const int idx = blockIdx.x * 256 + threadIdx.x;
    const int stride = gridDim.x * 256;
    const int ngroups = M_ * D_ / 8;
    const float4* in4 = (const float4*)in;
    for (int g = idx; g < ngroups; g += stride) {
        const float4 a = in4[2 * g];
        const float4 b = in4[2 * g + 1];
        out[g] = make_uint4(pack2(a.x, a.y), pack2(a.z, a.w),
                            pack2(b.x, b.y), pack2(b.z, b.w));
    }
}

// ---------- prep B: W_h [k][n] fp32 -> Wt [n][k] bf16 (transpose) ----------
__global__ __launch_bounds__(256) void conv_wt_kernel(
    const float* __restrict__ W_h, unsigned short* __restrict__ Wt)
{
    __shared__ float tile[64][65];
    const int k0 = (blockIdx.x & 15) * 64;
    const int n0 = (blockIdx.x >> 4) * 64;
    const int tx = threadIdx.x & 63, ty = threadIdx.x >> 6;
#pragma unroll
    for (int r = 0; r < 16; ++r) {
        const int row = ty * 16 + r;
        tile[row][tx] = W_h[(size_t)(k0 + row) * D_ + n0 + tx];
    }
    __syncthreads();
#pragma unroll
    for (int r = 0; r < 16; ++r) {
        const int row = ty * 16 + r;  // n index within tile
        Wt[(size_t)(n0 + row) * D_ + k0 + tx] = (unsigned short)f2bf(tile[tx][row]);
    }
}

// ---------- kernel 1: dec = s_t @ W_s + b_s  (B x D) ----------
__global__ __launch_bounds__(256) void dec_kernel(
    const float* __restrict__ s_t, const float* __restrict__ W_s,
    const float* __restrict__ b_s, float* __restrict__ dec)
{
    __shared__ float s_lds[D_];
    const int b = blockIdx.x >> 2;
    const int d = (blockIdx.x & 3) * 256 + threadIdx.x;
    for (int i = threadIdx.x; i < D_; i += 256) s_lds[i] = s_t[b * D_ + i];
    __syncthreads();
    float acc = b_s[d];
#pragma unroll 8
    for (int k = 0; k < D_; ++k) acc += s_lds[k] * W_s[(size_t)k * D_ + d];
    dec[b * D_ + d] = acc;
}

// ---------- kernel 2 (FAST): fused e_t GEMM via global_load_lds ----------
// LDS layout: linear [row][64] bf16, values stored with kbyte ^= (row&7)<<4
// (pre-swizzled on the GLOBAL source address; ds_read applies the same XOR).
__global__ __launch_bounds__(256, 2) void attn_gemm_fast(
    const unsigned short* __restrict__ h_bf, const unsigned short* __restrict__ wt_bf,
    const float* __restrict__ dec, const float* __restrict__ coverage,
    const float* __restrict__ W_c, const float* __restrict__ V_w,
    float* __restrict__ e_part)
{
    __shared__ __align__(16) unsigned short lA[BM_ * BK_];   // 16 KB
    __shared__ __align__(16) unsigned short lB[BN_ * BK_];   // 16 KB

    const int tid = threadIdx.x;
    const int nt = blockIdx.x >> 8;    // mt-inner: W_h panel stays L2-resident
    const int mt = blockIdx.x & 255;
    const int m0 = mt * BM_;
    const int n0 = nt * BN_;
    const int bb = m0 >> 10;

    const int wave = tid >> 6;
    const int lane = tid & 63;
    const int wr = wave >> 1, wc = wave & 1;
    const int lr = lane & 15;
    const int lk = lane >> 4;

    f32x4 acc[4][4];
    const f32x4 fzero = {0.f, 0.f, 0.f, 0.f};
#pragma unroll
    for (int i = 0; i < 4; ++i)
#pragma unroll
        for (int j = 0; j < 4; ++j) acc[i][j] = fzero;

    const char* gA = (const char*)h_bf + (size_t)m0 * (D_ * 2);
    const char* gB = (const char*)wt_bf + (size_t)n0 * (D_ * 2);
    const int lrow8 = lane >> 3;                         // sub-row within 8-row chunk
    const int scol = (((lane & 7) ^ lrow8) << 4);        // pre-swizzled source byte

    for (int k0 = 0; k0 < D_; k0 += BK_) {
        // stage: each wave issues 4 A-chunks + 4 B-chunks of 1 KB (8 rows x 128 B)
#pragma unroll
        for (int j = 0; j < 4; ++j) {
            const int c = 4 * wave + j;
            const int row = c * 8 + lrow8;
            const size_t goff = (size_t)row * (D_ * 2) + (size_t)k0 * 2 + scol;
            __builtin_amdgcn_global_load_lds(
                (const __attribute__((address_space(1))) void*)(gA + goff),
                (__attribute__((address_space(3))) void*)((char*)lA + c * 1024),
                16, 0, 0);
            __builtin_amdgcn_global_load_lds(
                (const __attribute__((address_space(1))) void*)(gB + goff),
                (__attribute__((address_space(3))) void*)((char*)lB + c * 1024),
                16, 0, 0);
        }
        __syncthreads();

        short8 af[2][4], bfr[2][4];
        const int sw = (lr & 7) << 4;
#pragma unroll
        for (int kk = 0; kk < 2; ++kk)
#pragma unroll
            for (int i = 0; i < 4; ++i) {
                const int ar = wr * 64 + i * 16 + lr;   // row&7 == lr&7
                const int br = wc * 64 + i * 16 + lr;
                const int kb = kk * 64 + lk * 16;
                af[kk][i]  = *(const short8*)((const char*)lA + ar * 128 + (kb ^ sw));
                bfr[kk][i] = *(const short8*)((const char*)lB + br * 128 + (kb ^ sw));
            }
#pragma unroll
        for (int kk = 0; kk < 2; ++kk)
#pragma unroll
            for (int mi = 0; mi < 4; ++mi)
#pragma unroll
                for (int ni = 0; ni < 4; ++ni)
                    acc[mi][ni] = __builtin_amdgcn_mfma_f32_16x16x32_bf16(
                        af[kk][mi], bfr[kk][ni], acc[mi][ni], 0, 0, 0);
        __syncthreads();
    }

    // epilogue: e += tanh(acc + dec[n] + cov[m]*W_c[n]) * V_w[n]
    float esum[4][4];
    float covv[4][4];
#pragma unroll
    for (int mi = 0; mi < 4; ++mi)
#pragma unroll
        for (int r = 0; r < 4; ++r) {
            esum[mi][r] = 0.f;
            covv[mi][r] = coverage[m0 + wr * 64 + mi * 16 + lk * 4 + r];
        }
    const float* decb = dec + bb * D_;
#pragma unroll
    for (int ni = 0; ni < 4; ++ni) {
        const int n = n0 + wc * 64 + ni * 16 + lr;   // C/D col = lane&15
        const float vw = V_w[n];
        const float dc = decb[n];
        const float wcv = W_c[n];
#pragma unroll
        for (int mi = 0; mi < 4; ++mi)
#pragma unroll
            for (int r = 0; r < 4; ++r) {
                const float f = acc[mi][ni][r] + dc + covv[mi][r] * wcv;
                esum[mi][r] += fast_tanh(f) * vw;
            }
    }
#pragma unroll
    for (int off = 1; off <= 8; off <<= 1)
#pragma unroll
        for (int mi = 0; mi < 4; ++mi)
#pragma unroll
            for (int r = 0; r < 4; ++r)
                esum[mi][r] += __shfl_xor(esum[mi][r], off, 64);

    float* e_lds = (float*)lA;
    if (lr == 0) {
#pragma unroll
        for (int mi = 0; mi < 4; ++mi)
#pragma unroll
            for (int r = 0; r < 4; ++r)
                e_lds[wc * 128 + wr * 64 + mi * 16 + lk * 4 + r] = esum[mi][r];
    }
    __syncthreads();
    if (tid < 128)
        e_part[(size_t)nt * M_ + m0 + tid] = e_lds[tid] + e_lds[128 + tid];
}

// ---------- kernel 2 (FALLBACK, round-1 reg-staged): used if ws too small ----------
__global__ __launch_bounds__(256, 2) void attn_gemm_kernel(
    const float* __restrict__ h_i, const float* __restrict__ W_h,
    const float* __restrict__ dec, const float* __restrict__ coverage,
    const float* __restrict__ W_c, const float* __restrict__ V_w,
    float* __restrict__ e_part)
{
    __shared__ __align__(16) unsigned short lA[BM_][LSTR];
    __shared__ __align__(16) unsigned short lB[BN_][LSTR];

    const int tid = threadIdx.x;
    const int nt = blockIdx.x >> 8;
    const int mt = blockIdx.x & 255;
    const int m0 = mt * BM_;
    const int n0 = nt * BN_;
    const int bb = m0 >> 10;

    const int wave = tid >> 6;
    const int lane = tid & 63;
    const int wr = wave >> 1, wc = wave & 1;
    const int lr = lane & 15;
    const int lk = lane >> 4;

    f32x4 acc[4][4];
    const f32x4 fzero = {0.f, 0.f, 0.f, 0.f};
#pragma unroll
    for (int i = 0; i < 4; ++i)
#pragma unroll
        for (int j = 0; j < 4; ++j) acc[i][j] = fzero;

    const int a_row = tid >> 4;
    const int a_k = (tid & 15) << 2;
    const float* hA = h_i + (size_t)m0 * D_;

    for (int k0 = 0; k0 < D_; k0 += BK_) {
#pragma unroll
        for (int p = 0; p < 8; ++p) {
            const int row = a_row + p * 16;
            const float4 v = *(const float4*)(hA + (size_t)row * D_ + (k0 + a_k));
            *(uint2*)&lA[row][a_k] = make_uint2(pack2(v.x, v.y), pack2(v.z, v.w));
        }
#pragma unroll
        for (int p = 0; p < 8; ++p) {
            const int task = tid + p * 256;
            const int n = task & 127;
            const int kg = task >> 7;
            const float* wp = W_h + (size_t)(k0 + kg * 4) * D_ + n0 + n;
            const float x0 = wp[0 * D_], x1 = wp[1 * D_], x2 = wp[2 * D_], x3 = wp[3 * D_];
            *(uint2*)&lB[n][kg * 4] = make_uint2(pack2(x0, x1), pack2(x2, x3));
        }
        __syncthreads();

        short8 af[2][4], bfr[2][4];
#pragma unroll
        for (int kk = 0; kk < 2; ++kk)
#pragma unroll
            for (int i = 0; i < 4; ++i) {
                af[kk][i]  = *(const short8*)&lA[wr * 64 + i * 16 + lr][kk * 32 + lk * 8];
                bfr[kk][i] = *(const short8*)&lB[wc * 64 + i * 16 + lr][kk * 32 + lk * 8];
            }
#pragma unroll
        for (int kk = 0; kk < 2; ++kk)
#pragma unroll
            for (int mi = 0; mi < 4; ++mi)
#pragma unroll
                for (int ni = 0; ni < 4; ++ni)
                    acc[mi][ni] = __builtin_amdgcn_mfma_f32_16x16x32_bf16(
                        af[kk][mi], bfr[kk][ni], acc[mi][ni], 0, 0, 0);
        __syncthreads();
    }

    float esum[4][4];
    float covv[4][4];
#pragma unroll
    for (int mi = 0; mi < 4; ++mi)
#pragma unroll
        for (int r = 0; r < 4; ++r) {
            esum[mi][r] = 0.f;
            covv[mi][r] = coverage[m0 + wr * 64 + mi * 16 + lk * 4 + r];
        }
    const float* decb = dec + bb * D_;
#pragma unroll
    for (int ni = 0; ni < 4; ++ni) {
        const int n = n0 + wc * 64 + ni * 16 + lr;
        const float vw = V_w[n];
        const float dc = decb[n];
        const float wcv = W_c[n];
#pragma unroll
        for (int mi = 0; mi < 4; ++mi)
#pragma unroll
            for (int r = 0; r < 4; ++r) {
                const float f = acc[mi][ni][r] + dc + covv[mi][r] * wcv;
                esum[mi][r] += fast_tanh(f) * vw;
            }
    }
#pragma unroll
    for (int off = 1; off <= 8; off <<= 1)
#pragma unroll
        for (int mi = 0; mi < 4; ++mi)
#pragma unroll
            for (int r = 0; r < 4; ++r)
                esum[mi][r] += __shfl_xor(esum[mi][r], off, 64);

    float* e_lds = (float*)&lA[0][0];
    if (lr == 0) {
#pragma unroll
        for (int mi = 0; mi < 4; ++mi)
#pragma unroll
            for (int r = 0; r < 4; ++r)
                e_lds[wc * 128 + wr * 64 + mi * 16 + lk * 4 + r] = esum[mi][r];
    }
    __syncthreads();
    if (tid < 128)
        e_part[(size_t)nt * M_ + m0 + tid] = e_lds[tid] + e_lds[128 + tid];
}

// ---------- kernel 3: softmax over T per batch + coverage_new ----------
__global__ __launch_bounds__(256) void softmax_kernel(
    const float* __restrict__ e_part, const float* __restrict__ coverage,
    float* __restrict__ a_out, float* __restrict__ cov_out)
{
    const int b = blockIdx.x;
    const int tid = threadIdx.x;
    __shared__ float redmx[4], redsum[4];
    float e[4];
#pragma unroll
    for (int j = 0; j < 4; ++j) {
        const int t = tid + j * 256;
        float s = 0.f;
#pragma unroll
        for (int p = 0; p < NT_; ++p) s += e_part[(size_t)p * M_ + b * T_ + t];
        e[j] = s;
    }
    float mx = fmaxf(fmaxf(e[0], e[1]), fmaxf(e[2], e[3]));
#pragma unroll
    for (int off = 32; off > 0; off >>= 1) mx = fmaxf(mx, __shfl_xor(mx, off, 64));
    if ((tid & 63) == 0) redmx[tid >> 6] = mx;
    __syncthreads();
    mx = fmaxf(fmaxf(redmx[0], redmx[1]), fmaxf(redmx[2], redmx[3]));
    float p4[4];
    float ps = 0.f;
#pragma unroll
    for (int j = 0; j < 4; ++j) { p4[j] = __expf(e[j] - mx); ps += p4[j]; }
#pragma unroll
    for (int off = 32; off > 0; off >>= 1) ps += __shfl_xor(ps, off, 64);
    if ((tid & 63) == 0) redsum[tid >> 6] = ps;
    __syncthreads();
    ps = redsum[0] + redsum[1] + redsum[2] + redsum[3];
    const float inv = __fdividef(1.f, ps);
#pragma unroll
    for (int j = 0; j < 4; ++j) {
        const int idx = b * T_ + tid + j * 256;
        const float a = p4[j] * inv;
        a_out[idx] = a;
        cov_out[idx] = coverage[idx] + a;
    }
}

// ---------- kernel 4: context partials over T-chunks ----------
__global__ __launch_bounds__(256) void ctx_part_kernel(
    const float* __restrict__ h_i, const float* __restrict__ a_t,
    float* __restrict__ ctx_part)
{
    const int bid = blockIdx.x;     // B * 4(dchunk) * 4(tchunk)
    const int b = bid >> 4;
    const int dc = (bid >> 2) & 3;
    const int tc = bid & 3;
    const int tid = threadIdx.x;
    const int d = dc * 256 + tid;
    __shared__ float a_lds[256];
    a_lds[tid] = a_t[b * T_ + tc * 256 + tid];
    __syncthreads();
    const float* hp = h_i + ((size_t)(b * T_ + tc * 256)) * D_ + d;
    float acc = 0.f;
#pragma unroll 8
    for (int t = 0; t < 256; ++t) acc += a_lds[t] * hp[(size_t)t * D_];
    ctx_part[tc * (B_ * D_) + b * D_ + d] = acc;
}

// ---------- kernel 5: reduce context partials ----------
__global__ __launch_bounds__(256) void ctx_reduce_kernel(
    const float* __restrict__ ctx_part, float* __restrict__ out)
{
    const int i = blockIdx.x * 256 + threadIdx.x;
    out[i] = ctx_part[i] + ctx_part[B_ * D_ + i] + ctx_part[2 * B_ * D_ + i] +
             ctx_part[3 * B_ * D_ + i];
}

extern "C" void kernel_launch(void* const* d_in, const int* in_sizes, int n_in,
                              void* d_out, int out_size, void* d_ws, size_t ws_size,
                              hipStream_t stream)
{
    (void)in_sizes; (void)n_in; (void)out_size;
    const float* h_i      = (const float*)d_in[0];
    const float* s_t      = (const float*)d_in[1];
    const float* coverage = (const float*)d_in[2];
    const float* W_h      = (const float*)d_in[3];
    const float* W_s      = (const float*)d_in[4];
    const float* b_s      = (const float*)d_in[5];
    const float* W_c      = (const float*)d_in[6];
    const float* V_w      = (const float*)d_in[7];

    float* out     = (float*)d_out;
    float* ctx_out = out;                 // (B, D)
    float* a_out   = out + B_ * T_;       // (B, T)
    float* cov_out = out + 2 * B_ * T_;   // (B, T)

    float* ws       = (float*)d_ws;
    float* dec      = ws;                       // B*D floats
    float* e_part   = ws + B_ * D_;             // NT_*M_ floats
    float* ctx_part = e_part + NT_ * M_;        // 4*B*D floats
    const size_t f32_count = (size_t)B_ * D_ + (size_t)NT_ * M_ + 4 * (size_t)B_ * D_;
    unsigned short* h_bf  = (unsigned short*)(ws + f32_count);          // M_*D_ bf16
    unsigned short* wt_bf = h_bf + (size_t)M_ * D_;                     // D_*D_ bf16
    const size_t need = f32_count * 4 + ((size_t)M_ * D_ + (size_t)D_ * D_) * 2;

    dec_kernel<<<B_ * 4, 256, 0, stream>>>(s_t, W_s, b_s, dec);
    if (ws_size >= need) {
        conv_h_kernel<<<2048, 256, 0, stream>>>(h_i, (uint4*)h_bf);
        conv_wt_kernel<<<256, 256, 0, stream>>>(W_h, wt_bf);
        attn_gemm_fast<<<NT_ * (M_ / BM_), 256, 0, stream>>>(h_bf, wt_bf, dec, coverage,
                                                             W_c, V_w, e_part);
    } else {
        attn_gemm_kernel<<<NT_ * (M_ / BM_), 256, 0, stream>>>(h_i, W_h, dec, coverage,
                                                               W_c, V_w, e_part);
    }
    softmax_kernel<<<B_, 256, 0, stream>>>(e_part, coverage, a_out, cov_out);
    ctx_part_kernel<<<B_ * 16, 256, 0, stream>>>(h_i, a_out, ctx_part);
    ctx_reduce_kernel<<<(B_ * D_) / 256, 256, 0, stream>>>(ctx_part, ctx_out);
}

// Round 3
// 185.574 us; speedup vs baseline: 1.3670x; 1.0301x over previous
//
#include <hip/hip_runtime.h>

#define B_ 32
#define T_ 1024
#define D_ 1024
#define M_ (B_ * T_)
#define NT_ 8
#define BM_ 128
#define BN_ 128
#define BK_ 64
#define NKT (D_ / BK_)
#define LSTR 72  // fallback-path LDS row stride (bf16 elems)

typedef __attribute__((ext_vector_type(8))) short short8;
typedef __attribute__((ext_vector_type(4))) float f32x4;

__device__ __forceinline__ unsigned f2bf(float f) {
    union { float f; unsigned u; } v; v.f = f;
    return (v.u + 0x7FFFu + ((v.u >> 16) & 1u)) >> 16;  // RNE
}
__device__ __forceinline__ unsigned pack2(float a, float b) {
    return f2bf(a) | (f2bf(b) << 16);
}
__device__ __forceinline__ float bf2f(unsigned hi16) {
    union { unsigned u; float f; } v; v.u = hi16 << 16;
    return v.f;
}
__device__ __forceinline__ float fast_tanh(float x) {
    x = fminf(15.0f, fmaxf(-15.0f, x));
    float e = __expf(2.0f * x);
    return (e - 1.0f) * __fdividef(1.0f, e + 1.0f);
}

// ---------- prep A: h_i fp32 -> bf16 (row-major) ----------
__global__ __launch_bounds__(256) void conv_h_kernel(
    const float* __restrict__ in, uint4* __restrict__ out)
{
    const int idx = blockIdx.x * 256 + threadIdx.x;
    const int stride = gridDim.x * 256;
    const int ngroups = M_ * D_ / 8;
    const float4* in4 = (const float4*)in;
    for (int g = idx; g < ngroups; g += stride) {
        const float4 a = in4[2 * g];
        const float4 b = in4[2 * g + 1];
        out[g] = make_uint4(pack2(a.x, a.y), pack2(a.z, a.w),
                            pack2(b.x, b.y), pack2(b.z, b.w));
    }
}

// ---------- prep B: W_h [k][n] fp32 -> Wt [n][k] bf16 (transpose) ----------
__global__ __launch_bounds__(256) void conv_wt_kernel(
    const float* __restrict__ W_h, unsigned short* __restrict__ Wt)
{
    __shared__ float tile[64][65];
    const int k0 = (blockIdx.x & 15) * 64;
    const int n0 = (blockIdx.x >> 4) * 64;
    const int tx = threadIdx.x & 63, ty = threadIdx.x >> 6;
#pragma unroll
    for (int r = 0; r < 16; ++r) {
        const int row = ty * 16 + r;
        tile[row][tx] = W_h[(size_t)(k0 + row) * D_ + n0 + tx];
    }
    __syncthreads();
#pragma unroll
    for (int r = 0; r < 16; ++r) {
        const int row = ty * 16 + r;  // n index within tile
        Wt[(size_t)(n0 + row) * D_ + k0 + tx] = (unsigned short)f2bf(tile[tx][row]);
    }
}

// ---------- kernel 1: dec partials, k-split x4: dec_part[kc][b][d] ----------
__global__ __launch_bounds__(256) void dec_kernel(
    const float* __restrict__ s_t, const float* __restrict__ W_s,
    const float* __restrict__ b_s, float* __restrict__ dec_part)
{
    const int bid = blockIdx.x;          // B_ * 4(nc) * 4(kc)
    const int kc = bid & 3;
    const int nc = (bid >> 2) & 3;
    const int b  = bid >> 4;
    const int d = nc * 256 + threadIdx.x;
    const int k0 = kc * 256;
    __shared__ float s_lds[256];
    s_lds[threadIdx.x] = s_t[b * D_ + k0 + threadIdx.x];
    __syncthreads();
    float acc = (kc == 0) ? b_s[d] : 0.f;
#pragma unroll 8
    for (int k = 0; k < 256; ++k) acc += s_lds[k] * W_s[(size_t)(k0 + k) * D_ + d];
    dec_part[kc * (B_ * D_) + b * D_ + d] = acc;
}

// ---------- kernel 2 (FAST): fused e_t GEMM, double-buffered global_load_lds ----------
__global__ __launch_bounds__(256, 2) void attn_gemm_fast(
    const unsigned short* __restrict__ h_bf, const unsigned short* __restrict__ wt_bf,
    const float* __restrict__ dec_part, const float* __restrict__ coverage,
    const float* __restrict__ W_c, const float* __restrict__ V_w,
    float* __restrict__ e_part)
{
    __shared__ __align__(16) unsigned short lA[2][BM_ * BK_];   // 2 x 16 KB
    __shared__ __align__(16) unsigned short lB[2][BN_ * BK_];   // 2 x 16 KB

    const int tid = threadIdx.x;
    const int nt = blockIdx.x >> 8;    // mt-inner: W_h panel stays L2-resident
    const int mt = blockIdx.x & 255;
    const int m0 = mt * BM_;
    const int n0 = nt * BN_;
    const int bb = m0 >> 10;

    const int wave = tid >> 6;
    const int lane = tid & 63;
    const int wr = wave >> 1, wc = wave & 1;
    const int lr = lane & 15;
    const int lk = lane >> 4;

    f32x4 acc[4][4];
    const f32x4 fzero = {0.f, 0.f, 0.f, 0.f};
#pragma unroll
    for (int i = 0; i < 4; ++i)
#pragma unroll
        for (int j = 0; j < 4; ++j) acc[i][j] = fzero;

    const char* gA = (const char*)h_bf + (size_t)m0 * (D_ * 2);
    const char* gB = (const char*)wt_bf + (size_t)n0 * (D_ * 2);
    const int lrow8 = lane >> 3;                   // sub-row within 8-row chunk
    const int scol = (((lane & 7) ^ lrow8) << 4);  // pre-swizzled source byte

#define STAGE(buf, k0)                                                             \
    {                                                                              \
        _Pragma("unroll")                                                          \
        for (int j = 0; j < 4; ++j) {                                              \
            const int c = 4 * wave + j;                                            \
            const int row = c * 8 + lrow8;                                         \
            const size_t goff = (size_t)row * (D_ * 2) + (size_t)(k0) * 2 + scol;  \
            __builtin_amdgcn_global_load_lds(                                      \
                (const __attribute__((address_space(1))) void*)(gA + goff),        \
                (__attribute__((address_space(3))) void*)((char*)lA[buf] + c * 1024), \
                16, 0, 0);                                                         \
            __builtin_amdgcn_global_load_lds(                                      \
                (const __attribute__((address_space(1))) void*)(gB + goff),        \
                (__attribute__((address_space(3))) void*)((char*)lB[buf] + c * 1024), \
                16, 0, 0);                                                         \
        }                                                                          \
    }

    STAGE(0, 0);
    __syncthreads();   // implicit vmcnt(0) drain -> buf0 ready

    const int sw = (lr & 7) << 4;
    for (int kt = 0; kt < NKT; ++kt) {
        const int cur = kt & 1;
        if (kt + 1 < NKT) STAGE(cur ^ 1, (kt + 1) * BK_);  // prefetch next tile

        short8 af[2][4], bfr[2][4];
#pragma unroll
        for (int kk = 0; kk < 2; ++kk)
#pragma unroll
            for (int i = 0; i < 4; ++i) {
                const int ar = wr * 64 + i * 16 + lr;   // row&7 == lr&7
                const int br = wc * 64 + i * 16 + lr;
                const int kb = kk * 64 + lk * 16;
                af[kk][i]  = *(const short8*)((const char*)lA[cur] + ar * 128 + (kb ^ sw));
                bfr[kk][i] = *(const short8*)((const char*)lB[cur] + br * 128 + (kb ^ sw));
            }
#pragma unroll
        for (int kk = 0; kk < 2; ++kk)
#pragma unroll
            for (int mi = 0; mi < 4; ++mi)
#pragma unroll
                for (int ni = 0; ni < 4; ++ni)
                    acc[mi][ni] = __builtin_amdgcn_mfma_f32_16x16x32_bf16(
                        af[kk][mi], bfr[kk][ni], acc[mi][ni], 0, 0, 0);
        __syncthreads();   // drains the prefetch (vmcnt 0) + protects WAR on buf cur
    }
#undef STAGE

    // epilogue: e += tanh(acc + dec[n] + cov[m]*W_c[n]) * V_w[n]
    float esum[4][4];
    float covv[4][4];
#pragma unroll
    for (int mi = 0; mi < 4; ++mi)
#pragma unroll
        for (int r = 0; r < 4; ++r) {
            esum[mi][r] = 0.f;
            covv[mi][r] = coverage[m0 + wr * 64 + mi * 16 + lk * 4 + r];
        }
    const float* dp = dec_part + bb * D_;
#pragma unroll
    for (int ni = 0; ni < 4; ++ni) {
        const int n = n0 + wc * 64 + ni * 16 + lr;   // C/D col = lane&15
        const float vw = V_w[n];
        const float dc = dp[n] + dp[B_ * D_ + n] + dp[2 * B_ * D_ + n] + dp[3 * B_ * D_ + n];
        const float wcv = W_c[n];
#pragma unroll
        for (int mi = 0; mi < 4; ++mi)
#pragma unroll
            for (int r = 0; r < 4; ++r) {
                const float f = acc[mi][ni][r] + dc + covv[mi][r] * wcv;
                esum[mi][r] += fast_tanh(f) * vw;
            }
    }
#pragma unroll
    for (int off = 1; off <= 8; off <<= 1)
#pragma unroll
        for (int mi = 0; mi < 4; ++mi)
#pragma unroll
            for (int r = 0; r < 4; ++r)
                esum[mi][r] += __shfl_xor(esum[mi][r], off, 64);

    float* e_lds = (float*)lA[0];
    if (lr == 0) {
#pragma unroll
        for (int mi = 0; mi < 4; ++mi)
#pragma unroll
            for (int r = 0; r < 4; ++r)
                e_lds[wc * 128 + wr * 64 + mi * 16 + lk * 4 + r] = esum[mi][r];
    }
    __syncthreads();
    if (tid < 128)
        e_part[(size_t)nt * M_ + m0 + tid] = e_lds[tid] + e_lds[128 + tid];
}

// ---------- kernel 2 (FALLBACK, reg-staged fp32 inputs) ----------
__global__ __launch_bounds__(256, 2) void attn_gemm_kernel(
    const float* __restrict__ h_i, const float* __restrict__ W_h,
    const float* __restrict__ dec_part, const float* __restrict__ coverage,
    const float* __restrict__ W_c, const float* __restrict__ V_w,
    float* __restrict__ e_part)
{
    __shared__ __align__(16) unsigned short lA[BM_][LSTR];
    __shared__ __align__(16) unsigned short lB[BN_][LSTR];

    const int tid = threadIdx.x;
    const int nt = blockIdx.x >> 8;
    const int mt = blockIdx.x & 255;
    const int m0 = mt * BM_;
    const int n0 = nt * BN_;
    const int bb = m0 >> 10;

    const int wave = tid >> 6;
    const int lane = tid & 63;
    const int wr = wave >> 1, wc = wave & 1;
    const int lr = lane & 15;
    const int lk = lane >> 4;

    f32x4 acc[4][4];
    const f32x4 fzero = {0.f, 0.f, 0.f, 0.f};
#pragma unroll
    for (int i = 0; i < 4; ++i)
#pragma unroll
        for (int j = 0; j < 4; ++j) acc[i][j] = fzero;

    const int a_row = tid >> 4;
    const int a_k = (tid & 15) << 2;
    const float* hA = h_i + (size_t)m0 * D_;

    for (int k0 = 0; k0 < D_; k0 += BK_) {
#pragma unroll
        for (int p = 0; p < 8; ++p) {
            const int row = a_row + p * 16;
            const float4 v = *(const float4*)(hA + (size_t)row * D_ + (k0 + a_k));
            *(uint2*)&lA[row][a_k] = make_uint2(pack2(v.x, v.y), pack2(v.z, v.w));
        }
#pragma unroll
        for (int p = 0; p < 8; ++p) {
            const int task = tid + p * 256;
            const int n = task & 127;
            const int kg = task >> 7;
            const float* wp = W_h + (size_t)(k0 + kg * 4) * D_ + n0 + n;
            const float x0 = wp[0 * D_], x1 = wp[1 * D_], x2 = wp[2 * D_], x3 = wp[3 * D_];
            *(uint2*)&lB[n][kg * 4] = make_uint2(pack2(x0, x1), pack2(x2, x3));
        }
        __syncthreads();

        short8 af[2][4], bfr[2][4];
#pragma unroll
        for (int kk = 0; kk < 2; ++kk)
#pragma unroll
            for (int i = 0; i < 4; ++i) {
                af[kk][i]  = *(const short8*)&lA[wr * 64 + i * 16 + lr][kk * 32 + lk * 8];
                bfr[kk][i] = *(const short8*)&lB[wc * 64 + i * 16 + lr][kk * 32 + lk * 8];
            }
#pragma unroll
        for (int kk = 0; kk < 2; ++kk)
#pragma unroll
            for (int mi = 0; mi < 4; ++mi)
#pragma unroll
                for (int ni = 0; ni < 4; ++ni)
                    acc[mi][ni] = __builtin_amdgcn_mfma_f32_16x16x32_bf16(
                        af[kk][mi], bfr[kk][ni], acc[mi][ni], 0, 0, 0);
        __syncthreads();
    }

    float esum[4][4];
    float covv[4][4];
#pragma unroll
    for (int mi = 0; mi < 4; ++mi)
#pragma unroll
        for (int r = 0; r < 4; ++r) {
            esum[mi][r] = 0.f;
            covv[mi][r] = coverage[m0 + wr * 64 + mi * 16 + lk * 4 + r];
        }
    const float* dp = dec_part + bb * D_;
#pragma unroll
    for (int ni = 0; ni < 4; ++ni) {
        const int n = n0 + wc * 64 + ni * 16 + lr;
        const float vw = V_w[n];
        const float dc = dp[n] + dp[B_ * D_ + n] + dp[2 * B_ * D_ + n] + dp[3 * B_ * D_ + n];
        const float wcv = W_c[n];
#pragma unroll
        for (int mi = 0; mi < 4; ++mi)
#pragma unroll
            for (int r = 0; r < 4; ++r) {
                const float f = acc[mi][ni][r] + dc + covv[mi][r] * wcv;
                esum[mi][r] += fast_tanh(f) * vw;
            }
    }
#pragma unroll
    for (int off = 1; off <= 8; off <<= 1)
#pragma unroll
        for (int mi = 0; mi < 4; ++mi)
#pragma unroll
            for (int r = 0; r < 4; ++r)
                esum[mi][r] += __shfl_xor(esum[mi][r], off, 64);

    float* e_lds = (float*)&lA[0][0];
    if (lr == 0) {
#pragma unroll
        for (int mi = 0; mi < 4; ++mi)
#pragma unroll
            for (int r = 0; r < 4; ++r)
                e_lds[wc * 128 + wr * 64 + mi * 16 + lk * 4 + r] = esum[mi][r];
    }
    __syncthreads();
    if (tid < 128)
        e_part[(size_t)nt * M_ + m0 + tid] = e_lds[tid] + e_lds[128 + tid];
}

// ---------- kernel 3: softmax over T per batch + coverage_new ----------
__global__ __launch_bounds__(256) void softmax_kernel(
    const float* __restrict__ e_part, const float* __restrict__ coverage,
    float* __restrict__ a_out, float* __restrict__ cov_out)
{
    const int b = blockIdx.x;
    const int tid = threadIdx.x;
    __shared__ float redmx[4], redsum[4];
    float e[4];
#pragma unroll
    for (int j = 0; j < 4; ++j) {
        const int t = tid + j * 256;
        float s = 0.f;
#pragma unroll
        for (int p = 0; p < NT_; ++p) s += e_part[(size_t)p * M_ + b * T_ + t];
        e[j] = s;
    }
    float mx = fmaxf(fmaxf(e[0], e[1]), fmaxf(e[2], e[3]));
#pragma unroll
    for (int off = 32; off > 0; off >>= 1) mx = fmaxf(mx, __shfl_xor(mx, off, 64));
    if ((tid & 63) == 0) redmx[tid >> 6] = mx;
    __syncthreads();
    mx = fmaxf(fmaxf(redmx[0], redmx[1]), fmaxf(redmx[2], redmx[3]));
    float p4[4];
    float ps = 0.f;
#pragma unroll
    for (int j = 0; j < 4; ++j) { p4[j] = __expf(e[j] - mx); ps += p4[j]; }
#pragma unroll
    for (int off = 32; off > 0; off >>= 1) ps += __shfl_xor(ps, off, 64);
    if ((tid & 63) == 0) redsum[tid >> 6] = ps;
    __syncthreads();
    ps = redsum[0] + redsum[1] + redsum[2] + redsum[3];
    const float inv = __fdividef(1.f, ps);
#pragma unroll
    for (int j = 0; j < 4; ++j) {
        const int idx = b * T_ + tid + j * 256;
        const float a = p4[j] * inv;
        a_out[idx] = a;
        cov_out[idx] = coverage[idx] + a;
    }
}

// ---------- kernel 4 (FAST): context partials from bf16 h ----------
__global__ __launch_bounds__(256) void ctx_part_bf(
    const unsigned short* __restrict__ h_bf, const float* __restrict__ a_t,
    float* __restrict__ ctx_part)
{
    const int bid = blockIdx.x;     // B * 2(dchunk) * 4(tchunk) = 256
    const int b = bid >> 3;
    const int dc = (bid >> 2) & 1;
    const int tc = bid & 3;
    const int tid = threadIdx.x;
    const int d0 = dc * 512 + tid * 2;
    __shared__ float a_lds[256];
    a_lds[tid] = a_t[b * T_ + tc * 256 + tid];
    __syncthreads();
    const unsigned short* hp = h_bf + ((size_t)(b * T_ + tc * 256)) * D_ + d0;
    float acc0 = 0.f, acc1 = 0.f;
#pragma unroll 8
    for (int t = 0; t < 256; ++t) {
        const unsigned v = *(const unsigned*)(hp + (size_t)t * D_);
        const float a = a_lds[t];
        acc0 += a * bf2f(v & 0xFFFFu);
        acc1 += a * bf2f(v >> 16);
    }
    *(float2*)(ctx_part + tc * (B_ * D_) + b * D_ + d0) = make_float2(acc0, acc1);
}

// ---------- kernel 4 (FALLBACK): context partials from fp32 h ----------
__global__ __launch_bounds__(256) void ctx_part_f32(
    const float* __restrict__ h_i, const float* __restrict__ a_t,
    float* __restrict__ ctx_part)
{
    const int bid = blockIdx.x;     // B * 4(dchunk) * 4(tchunk)
    const int b = bid >> 4;
    const int dc = (bid >> 2) & 3;
    const int tc = bid & 3;
    const int tid = threadIdx.x;
    const int d = dc * 256 + tid;
    __shared__ float a_lds[256];
    a_lds[tid] = a_t[b * T_ + tc * 256 + tid];
    __syncthreads();
    const float* hp = h_i + ((size_t)(b * T_ + tc * 256)) * D_ + d;
    float acc = 0.f;
#pragma unroll 8
    for (int t = 0; t < 256; ++t) acc += a_lds[t] * hp[(size_t)t * D_];
    ctx_part[tc * (B_ * D_) + b * D_ + d] = acc;
}

// ---------- kernel 5: reduce context partials ----------
__global__ __launch_bounds__(256) void ctx_reduce_kernel(
    const float* __restrict__ ctx_part, float* __restrict__ out)
{
    const int i = blockIdx.x * 256 + threadIdx.x;
    out[i] = ctx_part[i] + ctx_part[B_ * D_ + i] + ctx_part[2 * B_ * D_ + i] +
             ctx_part[3 * B_ * D_ + i];
}

extern "C" void kernel_launch(void* const* d_in, const int* in_sizes, int n_in,
                              void* d_out, int out_size, void* d_ws, size_t ws_size,
                              hipStream_t stream)
{
    (void)in_sizes; (void)n_in; (void)out_size;
    const float* h_i      = (const float*)d_in[0];
    const float* s_t      = (const float*)d_in[1];
    const float* coverage = (const float*)d_in[2];
    const float* W_h      = (const float*)d_in[3];
    const float* W_s      = (const float*)d_in[4];
    const float* b_s      = (const float*)d_in[5];
    const float* W_c      = (const float*)d_in[6];
    const float* V_w      = (const float*)d_in[7];

    float* out     = (float*)d_out;
    float* ctx_out = out;                 // (B, D)
    float* a_out   = out + B_ * T_;       // (B, T)
    float* cov_out = out + 2 * B_ * T_;   // (B, T)

    float* ws       = (float*)d_ws;
    float* dec_part = ws;                             // 4*B*D floats
    float* e_part   = dec_part + 4 * B_ * D_;         // NT_*M_ floats
    float* ctx_part = e_part + NT_ * M_;              // 4*B*D floats
    const size_t f32_count = 8 * (size_t)B_ * D_ + (size_t)NT_ * M_;
    unsigned short* h_bf  = (unsigned short*)(ws + f32_count);   // M_*D_ bf16
    unsigned short* wt_bf = h_bf + (size_t)M_ * D_;              // D_*D_ bf16
    const size_t need = f32_count * 4 + ((size_t)M_ * D_ + (size_t)D_ * D_) * 2;

    dec_kernel<<<B_ * 16, 256, 0, stream>>>(s_t, W_s, b_s, dec_part);
    if (ws_size >= need) {
        conv_h_kernel<<<2048, 256, 0, stream>>>(h_i, (uint4*)h_bf);
        conv_wt_kernel<<<256, 256, 0, stream>>>(W_h, wt_bf);
        attn_gemm_fast<<<NT_ * (M_ / BM_), 256, 0, stream>>>(h_bf, wt_bf, dec_part,
                                                             coverage, W_c, V_w, e_part);
        softmax_kernel<<<B_, 256, 0, stream>>>(e_part, coverage, a_out, cov_out);
        ctx_part_bf<<<B_ * 8, 256, 0, stream>>>(h_bf, a_out, ctx_part);
    } else {
        attn_gemm_kernel<<<NT_ * (M_ / BM_), 256, 0, stream>>>(h_i, W_h, dec_part,
                                                               coverage, W_c, V_w, e_part);
        softmax_kernel<<<B_, 256, 0, stream>>>(e_part, coverage, a_out, cov_out);
        ctx_part_f32<<<B_ * 16, 256, 0, stream>>>(h_i, a_out, ctx_part);
    }
    ctx_reduce_kernel<<<(B_ * D_) / 256, 256, 0, stream>>>(ctx_part, ctx_out);
}

// Round 5
// 157.270 us; speedup vs baseline: 1.6130x; 1.1800x over previous
//
#include <hip/hip_runtime.h>

#define B_ 32
#define T_ 1024
#define D_ 1024
#define M_ (B_ * T_)
#define NT_ 8
#define BM_ 128
#define BN_ 128
#define BK_ 64
#define NKT (D_ / BK_)
#define LSTR 72  // fallback-path LDS row stride (bf16 elems)

// Explicit full memory-counter drain before barriers in the DMA-staged GEMM.
#define FENCE_ALL() asm volatile("s_waitcnt vmcnt(0) lgkmcnt(0)" ::: "memory")

typedef __attribute__((ext_vector_type(8))) short short8;
typedef __attribute__((ext_vector_type(4))) float f32x4;

__device__ __forceinline__ unsigned f2bf(float f) {
    union { float f; unsigned u; } v; v.f = f;
    return (v.u + 0x7FFFu + ((v.u >> 16) & 1u)) >> 16;  // RNE
}
__device__ __forceinline__ unsigned pack2(float a, float b) {
    return f2bf(a) | (f2bf(b) << 16);
}
__device__ __forceinline__ float bf2f(unsigned hi16) {
    union { unsigned u; float f; } v; v.u = hi16 << 16;
    return v.f;
}
__device__ __forceinline__ float fast_tanh(float x) {
    x = fminf(15.0f, fmaxf(-15.0f, x));
    float e = __expf(2.0f * x);
    return (e - 1.0f) * __fdividef(1.0f, e + 1.0f);
}

// ---------- prep A: h_i fp32 -> bf16 (row-major) ----------
__global__ __launch_bounds__(256) void conv_h_kernel(
    const float* __restrict__ in, uint4* __restrict__ out)
{
    const int idx = blockIdx.x * 256 + threadIdx.x;
    const int stride = gridDim.x * 256;
    const int ngroups = M_ * D_ / 8;
    const float4* in4 = (const float4*)in;
    for (int g = idx; g < ngroups; g += stride) {
        const float4 a = in4[2 * g];
        const float4 b = in4[2 * g + 1];
        out[g] = make_uint4(pack2(a.x, a.y), pack2(a.z, a.w),
                            pack2(b.x, b.y), pack2(b.z, b.w));
    }
}

// ---------- prep B: W_h [k][n] fp32 -> Wt [n][k] bf16 (transpose) ----------
__global__ __launch_bounds__(256) void conv_wt_kernel(
    const float* __restrict__ W_h, unsigned short* __restrict__ Wt)
{
    __shared__ float tile[64][65];
    const int k0 = (blockIdx.x & 15) * 64;
    const int n0 = (blockIdx.x >> 4) * 64;
    const int tx = threadIdx.x & 63, ty = threadIdx.x >> 6;
#pragma unroll
    for (int r = 0; r < 16; ++r) {
        const int row = ty * 16 + r;
        tile[row][tx] = W_h[(size_t)(k0 + row) * D_ + n0 + tx];
    }
    __syncthreads();
#pragma unroll
    for (int r = 0; r < 16; ++r) {
        const int row = ty * 16 + r;  // n index within tile
        Wt[(size_t)(n0 + row) * D_ + k0 + tx] = (unsigned short)f2bf(tile[tx][row]);
    }
}

// ---------- kernel 1: dec partials, k-split x4: dec_part[kc][b][d] ----------
__global__ __launch_bounds__(256) void dec_kernel(
    const float* __restrict__ s_t, const float* __restrict__ W_s,
    const float* __restrict__ b_s, float* __restrict__ dec_part)
{
    const int bid = blockIdx.x;          // B_ * 4(nc) * 4(kc)
    const int kc = bid & 3;
    const int nc = (bid >> 2) & 3;
    const int b  = bid >> 4;
    const int d = nc * 256 + threadIdx.x;
    const int k0 = kc * 256;
    __shared__ float s_lds[256];
    s_lds[threadIdx.x] = s_t[b * D_ + k0 + threadIdx.x];
    __syncthreads();
    float acc = (kc == 0) ? b_s[d] : 0.f;
#pragma unroll 8
    for (int k = 0; k < 256; ++k) acc += s_lds[k] * W_s[(size_t)(k0 + k) * D_ + d];
    dec_part[kc * (B_ * D_) + b * D_ + d] = acc;
}

// ---------- kernel 2 (FAST): fused e_t GEMM, single-buffer global_load_lds ----------
// Hardened: explicit vmcnt/lgkmcnt fences before barriers; dedicated epilogue LDS.
__global__ __launch_bounds__(256, 2) void attn_gemm_fast(
    const unsigned short* __restrict__ h_bf, const unsigned short* __restrict__ wt_bf,
    const float* __restrict__ dec_part, const float* __restrict__ coverage,
    const float* __restrict__ W_c, const float* __restrict__ V_w,
    float* __restrict__ e_part)
{
    __shared__ __align__(16) unsigned short lA[BM_ * BK_];   // 16 KB
    __shared__ __align__(16) unsigned short lB[BN_ * BK_];   // 16 KB
    __shared__ float e_red[256];                              // dedicated epilogue scratch

    const int tid = threadIdx.x;
    const int nt = blockIdx.x >> 8;    // mt-inner: W_h panel stays L2-resident
    const int mt = blockIdx.x & 255;
    const int m0 = mt * BM_;
    const int n0 = nt * BN_;
    const int bb = m0 >> 10;

    const int wave = tid >> 6;
    const int lane = tid & 63;
    const int wr = wave >> 1, wc = wave & 1;
    const int lr = lane & 15;
    const int lk = lane >> 4;

    f32x4 acc[4][4];
    const f32x4 fzero = {0.f, 0.f, 0.f, 0.f};
#pragma unroll
    for (int i = 0; i < 4; ++i)
#pragma unroll
        for (int j = 0; j < 4; ++j) acc[i][j] = fzero;

    const char* gA = (const char*)h_bf + (size_t)m0 * (D_ * 2);
    const char* gB = (const char*)wt_bf + (size_t)n0 * (D_ * 2);
    const int lrow8 = lane >> 3;                   // sub-row within 8-row chunk
    const int scol = (((lane & 7) ^ lrow8) << 4);  // pre-swizzled source byte

    for (int k0 = 0; k0 < D_; k0 += BK_) {
        // stage: each wave issues 4 A-chunks + 4 B-chunks of 1 KB (8 rows x 128 B)
#pragma unroll
        for (int j = 0; j < 4; ++j) {
            const int c = 4 * wave + j;
            const int row = c * 8 + lrow8;
            const size_t goff = (size_t)row * (D_ * 2) + (size_t)k0 * 2 + scol;
            __builtin_amdgcn_global_load_lds(
                (const __attribute__((address_space(1))) void*)(gA + goff),
                (__attribute__((address_space(3))) void*)((char*)lA + c * 1024),
                16, 0, 0);
            __builtin_amdgcn_global_load_lds(
                (const __attribute__((address_space(1))) void*)(gB + goff),
                (__attribute__((address_space(3))) void*)((char*)lB + c * 1024),
                16, 0, 0);
        }
        FENCE_ALL();
        __syncthreads();

        short8 af[2][4], bfr[2][4];
        const int sw = (lr & 7) << 4;
#pragma unroll
        for (int kk = 0; kk < 2; ++kk)
#pragma unroll
            for (int i = 0; i < 4; ++i) {
                const int ar = wr * 64 + i * 16 + lr;   // row&7 == lr&7
                const int br = wc * 64 + i * 16 + lr;
                const int kb = kk * 64 + lk * 16;
                af[kk][i]  = *(const short8*)((const char*)lA + ar * 128 + (kb ^ sw));
                bfr[kk][i] = *(const short8*)((const char*)lB + br * 128 + (kb ^ sw));
            }
#pragma unroll
        for (int kk = 0; kk < 2; ++kk)
#pragma unroll
            for (int mi = 0; mi < 4; ++mi)
#pragma unroll
                for (int ni = 0; ni < 4; ++ni)
                    acc[mi][ni] = __builtin_amdgcn_mfma_f32_16x16x32_bf16(
                        af[kk][mi], bfr[kk][ni], acc[mi][ni], 0, 0, 0);
        FENCE_ALL();
        __syncthreads();
    }

    // epilogue: e += tanh(acc + dec[n] + cov[m]*W_c[n]) * V_w[n]
    float esum[4][4];
    float covv[4][4];
#pragma unroll
    for (int mi = 0; mi < 4; ++mi)
#pragma unroll
        for (int r = 0; r < 4; ++r) {
            esum[mi][r] = 0.f;
            covv[mi][r] = coverage[m0 + wr * 64 + mi * 16 + lk * 4 + r];
        }
    const float* dp = dec_part + bb * D_;
#pragma unroll
    for (int ni = 0; ni < 4; ++ni) {
        const int n = n0 + wc * 64 + ni * 16 + lr;   // C/D col = lane&15
        const float vw = V_w[n];
        const float dc = dp[n] + dp[B_ * D_ + n] + dp[2 * B_ * D_ + n] + dp[3 * B_ * D_ + n];
        const float wcv = W_c[n];
#pragma unroll
        for (int mi = 0; mi < 4; ++mi)
#pragma unroll
            for (int r = 0; r < 4; ++r) {
                const float f = acc[mi][ni][r] + dc + covv[mi][r] * wcv;
                esum[mi][r] += fast_tanh(f) * vw;
            }
    }
#pragma unroll
    for (int off = 1; off <= 8; off <<= 1)
#pragma unroll
        for (int mi = 0; mi < 4; ++mi)
#pragma unroll
            for (int r = 0; r < 4; ++r)
                esum[mi][r] += __shfl_xor(esum[mi][r], off, 64);

    if (lr == 0) {
#pragma unroll
        for (int mi = 0; mi < 4; ++mi)
#pragma unroll
            for (int r = 0; r < 4; ++r)
                e_red[wc * 128 + wr * 64 + mi * 16 + lk * 4 + r] = esum[mi][r];
    }
    FENCE_ALL();
    __syncthreads();
    if (tid < 128)
        e_part[(size_t)nt * M_ + m0 + tid] = e_red[tid] + e_red[128 + tid];
}

// ---------- kernel 2 (FALLBACK, reg-staged fp32 inputs) ----------
__global__ __launch_bounds__(256, 2) void attn_gemm_kernel(
    const float* __restrict__ h_i, const float* __restrict__ W_h,
    const float* __restrict__ dec_part, const float* __restrict__ coverage,
    const float* __restrict__ W_c, const float* __restrict__ V_w,
    float* __restrict__ e_part)
{
    __shared__ __align__(16) unsigned short lA[BM_][LSTR];
    __shared__ __align__(16) unsigned short lB[BN_][LSTR];
    __shared__ float e_red[256];

    const int tid = threadIdx.x;
    const int nt = blockIdx.x >> 8;
    const int mt = blockIdx.x & 255;
    const int m0 = mt * BM_;
    const int n0 = nt * BN_;
    const int bb = m0 >> 10;

    const int wave = tid >> 6;
    const int lane = tid & 63;
    const int wr = wave >> 1, wc = wave & 1;
    const int lr = lane & 15;
    const int lk = lane >> 4;

    f32x4 acc[4][4];
    const f32x4 fzero = {0.f, 0.f, 0.f, 0.f};
#pragma unroll
    for (int i = 0; i < 4; ++i)
#pragma unroll
        for (int j = 0; j < 4; ++j) acc[i][j] = fzero;

    const int a_row = tid >> 4;
    const int a_k = (tid & 15) << 2;
    const float* hA = h_i + (size_t)m0 * D_;

    for (int k0 = 0; k0 < D_; k0 += BK_) {
#pragma unroll
        for (int p = 0; p < 8; ++p) {
            const int row = a_row + p * 16;
            const float4 v = *(const float4*)(hA + (size_t)row * D_ + (k0 + a_k));
            *(uint2*)&lA[row][a_k] = make_uint2(pack2(v.x, v.y), pack2(v.z, v.w));
        }
#pragma unroll
        for (int p = 0; p < 8; ++p) {
            const int task = tid + p * 256;
            const int n = task & 127;
            const int kg = task >> 7;
            const float* wp = W_h + (size_t)(k0 + kg * 4) * D_ + n0 + n;
            const float x0 = wp[0 * D_], x1 = wp[1 * D_], x2 = wp[2 * D_], x3 = wp[3 * D_];
            *(uint2*)&lB[n][kg * 4] = make_uint2(pack2(x0, x1), pack2(x2, x3));
        }
        __syncthreads();

        short8 af[2][4], bfr[2][4];
#pragma unroll
        for (int kk = 0; kk < 2; ++kk)
#pragma unroll
            for (int i = 0; i < 4; ++i) {
                af[kk][i]  = *(const short8*)&lA[wr * 64 + i * 16 + lr][kk * 32 + lk * 8];
                bfr[kk][i] = *(const short8*)&lB[wc * 64 + i * 16 + lr][kk * 32 + lk * 8];
            }
#pragma unroll
        for (int kk = 0; kk < 2; ++kk)
#pragma unroll
            for (int mi = 0; mi < 4; ++mi)
#pragma unroll
                for (int ni = 0; ni < 4; ++ni)
                    acc[mi][ni] = __builtin_amdgcn_mfma_f32_16x16x32_bf16(
                        af[kk][mi], bfr[kk][ni], acc[mi][ni], 0, 0, 0);
        __syncthreads();
    }

    float esum[4][4];
    float covv[4][4];
#pragma unroll
    for (int mi = 0; mi < 4; ++mi)
#pragma unroll
        for (int r = 0; r < 4; ++r) {
            esum[mi][r] = 0.f;
            covv[mi][r] = coverage[m0 + wr * 64 + mi * 16 + lk * 4 + r];
        }
    const float* dp = dec_part + bb * D_;
#pragma unroll
    for (int ni = 0; ni < 4; ++ni) {
        const int n = n0 + wc * 64 + ni * 16 + lr;
        const float vw = V_w[n];
        const float dc = dp[n] + dp[B_ * D_ + n] + dp[2 * B_ * D_ + n] + dp[3 * B_ * D_ + n];
        const float wcv = W_c[n];
#pragma unroll
        for (int mi = 0; mi < 4; ++mi)
#pragma unroll
            for (int r = 0; r < 4; ++r) {
                const float f = acc[mi][ni][r] + dc + covv[mi][r] * wcv;
                esum[mi][r] += fast_tanh(f) * vw;
            }
    }
#pragma unroll
    for (int off = 1; off <= 8; off <<= 1)
#pragma unroll
        for (int mi = 0; mi < 4; ++mi)
#pragma unroll
            for (int r = 0; r < 4; ++r)
                esum[mi][r] += __shfl_xor(esum[mi][r], off, 64);

    if (lr == 0) {
#pragma unroll
        for (int mi = 0; mi < 4; ++mi)
#pragma unroll
            for (int r = 0; r < 4; ++r)
                e_red[wc * 128 + wr * 64 + mi * 16 + lk * 4 + r] = esum[mi][r];
    }
    __syncthreads();
    if (tid < 128)
        e_part[(size_t)nt * M_ + m0 + tid] = e_red[tid] + e_red[128 + tid];
}

// ---------- kernel 3: softmax over T per batch + coverage_new ----------
// Writes a_t to BOTH d_out and workspace (a_ws); downstream reads a_ws only.
__global__ __launch_bounds__(256) void softmax_kernel(
    const float* __restrict__ e_part, const float* __restrict__ coverage,
    float* __restrict__ a_out, float* __restrict__ cov_out,
    float* __restrict__ a_ws)
{
    const int b = blockIdx.x;
    const int tid = threadIdx.x;
    __shared__ float redmx[4], redsum[4];
    float e[4];
#pragma unroll
    for (int j = 0; j < 4; ++j) {
        const int t = tid + j * 256;
        float s = 0.f;
#pragma unroll
        for (int p = 0; p < NT_; ++p) s += e_part[(size_t)p * M_ + b * T_ + t];
        e[j] = s;
    }
    float mx = fmaxf(fmaxf(e[0], e[1]), fmaxf(e[2], e[3]));
#pragma unroll
    for (int off = 32; off > 0; off >>= 1) mx = fmaxf(mx, __shfl_xor(mx, off, 64));
    if ((tid & 63) == 0) redmx[tid >> 6] = mx;
    __syncthreads();
    mx = fmaxf(fmaxf(redmx[0], redmx[1]), fmaxf(redmx[2], redmx[3]));
    float p4[4];
    float ps = 0.f;
#pragma unroll
    for (int j = 0; j < 4; ++j) { p4[j] = __expf(e[j] - mx); ps += p4[j]; }
#pragma unroll
    for (int off = 32; off > 0; off >>= 1) ps += __shfl_xor(ps, off, 64);
    if ((tid & 63) == 0) redsum[tid >> 6] = ps;
    __syncthreads();
    ps = redsum[0] + redsum[1] + redsum[2] + redsum[3];
    const float inv = __fdividef(1.f, ps);
#pragma unroll
    for (int j = 0; j < 4; ++j) {
        const int idx = b * T_ + tid + j * 256;
        const float a = p4[j] * inv;
        a_out[idx] = a;
        a_ws[idx] = a;
        cov_out[idx] = coverage[idx] + a;
    }
}

// ---------- kernel 4 (FAST): context partials from bf16 h ----------
__global__ __launch_bounds__(256) void ctx_part_bf(
    const unsigned short* __restrict__ h_bf, const float* __restrict__ a_t,
    float* __restrict__ ctx_part)
{
    const int bid = blockIdx.x;     // B * 2(dchunk) * 4(tchunk) = 256
    const int b = bid >> 3;
    const int dc = (bid >> 2) & 1;
    const int tc = bid & 3;
    const int tid = threadIdx.x;
    const int d0 = dc * 512 + tid * 2;
    __shared__ float a_lds[256];
    a_lds[tid] = a_t[b * T_ + tc * 256 + tid];
    __syncthreads();
    const unsigned short* hp = h_bf + ((size_t)(b * T_ + tc * 256)) * D_ + d0;
    float acc0 = 0.f, acc1 = 0.f;
#pragma unroll 8
    for (int t = 0; t < 256; ++t) {
        const unsigned v = *(const unsigned*)(hp + (size_t)t * D_);
        const float a = a_lds[t];
        acc0 += a * bf2f(v & 0xFFFFu);
        acc1 += a * bf2f(v >> 16);
    }
    *(float2*)(ctx_part + tc * (B_ * D_) + b * D_ + d0) = make_float2(acc0, acc1);
}

// ---------- kernel 4 (FALLBACK): context partials from fp32 h ----------
__global__ __launch_bounds__(256) void ctx_part_f32(
    const float* __restrict__ h_i, const float* __restrict__ a_t,
    float* __restrict__ ctx_part)
{
    const int bid = blockIdx.x;     // B * 4(dchunk) * 4(tchunk)
    const int b = bid >> 4;
    const int dc = (bid >> 2) & 3;
    const int tc = bid & 3;
    const int tid = threadIdx.x;
    const int d = dc * 256 + tid;
    __shared__ float a_lds[256];
    a_lds[tid] = a_t[b * T_ + tc * 256 + tid];
    __syncthreads();
    const float* hp = h_i + ((size_t)(b * T_ + tc * 256)) * D_ + d;
    float acc = 0.f;
#pragma unroll 8
    for (int t = 0; t < 256; ++t) acc += a_lds[t] * hp[(size_t)t * D_];
    ctx_part[tc * (B_ * D_) + b * D_ + d] = acc;
}

// ---------- kernel 5: reduce context partials ----------
__global__ __launch_bounds__(256) void ctx_reduce_kernel(
    const float* __restrict__ ctx_part, float* __restrict__ out)
{
    const int i = blockIdx.x * 256 + threadIdx.x;
    out[i] = ctx_part[i] + ctx_part[B_ * D_ + i] + ctx_part[2 * B_ * D_ + i] +
             ctx_part[3 * B_ * D_ + i];
}

extern "C" void kernel_launch(void* const* d_in, const int* in_sizes, int n_in,
                              void* d_out, int out_size, void* d_ws, size_t ws_size,
                              hipStream_t stream)
{
    (void)in_sizes; (void)n_in; (void)out_size;
    const float* h_i      = (const float*)d_in[0];
    const float* s_t      = (const float*)d_in[1];
    const float* coverage = (const float*)d_in[2];
    const float* W_h      = (const float*)d_in[3];
    const float* W_s      = (const float*)d_in[4];
    const float* b_s      = (const float*)d_in[5];
    const float* W_c      = (const float*)d_in[6];
    const float* V_w      = (const float*)d_in[7];

    float* out     = (float*)d_out;
    float* ctx_out = out;                 // (B, D)
    float* a_out   = out + B_ * T_;       // (B, T)
    float* cov_out = out + 2 * B_ * T_;   // (B, T)

    float* ws       = (float*)d_ws;
    float* dec_part = ws;                             // 4*B*D floats
    float* e_part   = dec_part + 4 * B_ * D_;         // NT_*M_ floats
    float* ctx_part = e_part + NT_ * M_;              // 4*B*D floats
    float* a_ws     = ctx_part + 4 * B_ * D_;         // B*T floats
    const size_t f32_count = 8 * (size_t)B_ * D_ + (size_t)NT_ * M_ + (size_t)B_ * T_;
    unsigned short* h_bf  = (unsigned short*)(ws + f32_count);   // M_*D_ bf16
    unsigned short* wt_bf = h_bf + (size_t)M_ * D_;              // D_*D_ bf16
    const size_t need = f32_count * 4 + ((size_t)M_ * D_ + (size_t)D_ * D_) * 2;

    dec_kernel<<<B_ * 16, 256, 0, stream>>>(s_t, W_s, b_s, dec_part);
    if (ws_size >= need) {
        conv_h_kernel<<<2048, 256, 0, stream>>>(h_i, (uint4*)h_bf);
        conv_wt_kernel<<<256, 256, 0, stream>>>(W_h, wt_bf);
        attn_gemm_fast<<<NT_ * (M_ / BM_), 256, 0, stream>>>(h_bf, wt_bf, dec_part,
                                                             coverage, W_c, V_w, e_part);
        softmax_kernel<<<B_, 256, 0, stream>>>(e_part, coverage, a_out, cov_out, a_ws);
        ctx_part_bf<<<B_ * 8, 256, 0, stream>>>(h_bf, a_ws, ctx_part);
    } else {
        attn_gemm_kernel<<<NT_ * (M_ / BM_), 256, 0, stream>>>(h_i, W_h, dec_part,
                                                               coverage, W_c, V_w, e_part);
        softmax_kernel<<<B_, 256, 0, stream>>>(e_part, coverage, a_out, cov_out, a_ws);
        ctx_part_f32<<<B_ * 16, 256, 0, stream>>>(h_i, a_ws, ctx_part);
    }
    ctx_reduce_kernel<<<(B_ * D_) / 256, 256, 0, stream>>>(ctx_part, ctx_out);
}